// Round 13
// baseline (5870.157 us; speedup 1.0000x reference)
//
#include <hip/hip_runtime.h>
#include <hip/hip_bf16.h>
#include <stdint.h>

#define TK 64
#define FDIM 16384
#define DDIM 2048
#define NCAP 128
#define CCAP 384
#define SLOTS 12
#define TCAND 2.25f

typedef __attribute__((ext_vector_type(8))) short bf16x8;
typedef __attribute__((ext_vector_type(4))) float f32x4;

#define GLL(g, p)                                                        \
  __builtin_amdgcn_global_load_lds(                                      \
      (const __attribute__((address_space(1))) uint32_t*)(g),            \
      (__attribute__((address_space(3))) uint32_t*)(p), 16, 0, 0)

__device__ __forceinline__ unsigned short f2bf(float a) {
  union { float f; uint32_t u; } p; p.f = a;
  uint32_t u = p.u;
  return (unsigned short)((u + 0x7FFFu + ((u >> 16) & 1u)) >> 16);
}
__device__ __forceinline__ float bf2f(unsigned short h) {
  union { uint32_t u; float f; } p; p.u = ((uint32_t)h) << 16; return p.f;
}

// ---------------------------------------------------------------------------
__global__ __launch_bounds__(256) void conv_x(
    const float* __restrict__ x, unsigned short* __restrict__ xh, int n4)
{
  int i = blockIdx.x * 256 + threadIdx.x;
  const int stride = gridDim.x * 256;
  for (; i < n4; i += stride) {
    float4 v = ((const float4*)x)[i];
    ushort4 h;
    h.x = f2bf(v.x); h.y = f2bf(v.y); h.z = f2bf(v.z); h.w = f2bf(v.w);
    ((ushort4*)xh)[i] = h;
  }
}

// ---------------------------------------------------------------------------
__global__ __launch_bounds__(256) void conv_w(
    const float* __restrict__ W, float* __restrict__ wtf,
    unsigned short* __restrict__ wh)
{
  __shared__ float t[32][33];
  const int f0 = blockIdx.x * 32, d0 = blockIdx.y * 32;
  const int tr = threadIdx.x >> 3;
  const int tc = (threadIdx.x & 7) * 4;
  float4 v = *(const float4*)(W + (size_t)(d0 + tr) * FDIM + f0 + tc);
  t[tr][tc + 0] = v.x; t[tr][tc + 1] = v.y;
  t[tr][tc + 2] = v.z; t[tr][tc + 3] = v.w;
  __syncthreads();
  float a0 = t[tc + 0][tr], a1 = t[tc + 1][tr];
  float a2 = t[tc + 2][tr], a3 = t[tc + 3][tr];
  *(float4*)(wtf + (size_t)(f0 + tr) * DDIM + d0 + tc) =
      make_float4(a0, a1, a2, a3);
  ushort4 h;
  h.x = f2bf(a0); h.y = f2bf(a1); h.z = f2bf(a2); h.w = f2bf(a3);
  *(ushort4*)(wh + (size_t)(f0 + tr) * DDIM + d0 + tc) = h;
}

// ---------------------------------------------------------------------------
__global__ __launch_bounds__(256) void conv_wd(
    const float* __restrict__ W, unsigned short* __restrict__ Wb, int n4)
{
  int i = blockIdx.x * 256 + threadIdx.x;
  const int stride = gridDim.x * 256;
  for (; i < n4; i += stride) {
    float4 v = ((const float4*)W)[i];
    ushort4 h;
    h.x = f2bf(v.x); h.y = f2bf(v.y); h.z = f2bf(v.z); h.w = f2bf(v.w);
    ((ushort4*)Wb)[i] = h;
  }
}

// ---------------------------------------------------------------------------
// Kernel 1: encode GEMM, 256x256 tile, 8 waves (2Mx4N), BK=32, DOUBLE-buffer
// LDS (64 KB) so 2 blocks co-reside per CU — block A's MFMA overlaps block
// B's LDS/barrier phase (R12 post-mortem: lockstep 1-block/CU alternated
// pipes; 2696 cyc/K-step ~ LDS 1150 + MFMA 1242 serialized).
// Schedule: vmcnt(0); barrier; STAGE(s+1) (WAR barrier-fenced); reads; MFMA.
// STAGE(s+1) issued a full K-step before its vmcnt -> L2 latency hidden.
// ---------------------------------------------------------------------------
#define STAGE(T) do {                                                        \
    const int rb_ = (T) & 1;                                                 \
    const size_t ko_ = (size_t)(T) * 64;                                     \
    const size_t rA0 = (size_t)(row0 + sr4) * 4096 + ko_ + sgo;              \
    GLL(gx + rA0, smem + rb_ * 32768 + wq);                                  \
    const size_t rB0 = (size_t)(col0 + sr4) * 4096 + ko_ + sgo;              \
    GLL(gw + rB0, smem + rb_ * 32768 + 16384 + wq);                          \
    const size_t rA1 = (size_t)(row0 + 128 + sr4) * 4096 + ko_ + sgo;        \
    GLL(gx + rA1, smem + rb_ * 32768 + 8192 + wq);                           \
    const size_t rB1 = (size_t)(col0 + 128 + sr4) * 4096 + ko_ + sgo;        \
    GLL(gw + rB1, smem + rb_ * 32768 + 16384 + 8192 + wq);                   \
  } while (0)

#define KSTEP(S, DOSTAGE) do {                                               \
    asm volatile("s_waitcnt vmcnt(0)" ::: "memory");                         \
    __builtin_amdgcn_s_barrier();                                            \
    if (DOSTAGE) STAGE((S) + 1);                                             \
    const char* tb_ = smem + ((S) & 1) * 32768;                              \
    bf16x8 af[8], bg[4];                                                     \
    _Pragma("unroll") for (int m = 0; m < 8; ++m)                            \
      af[m] = *(const bf16x8*)(tb_ + awm + m * 1024 + lb);                   \
    _Pragma("unroll") for (int n = 0; n < 4; ++n)                            \
      bg[n] = *(const bf16x8*)(tb_ + 16384 + bwn + n * 1024 + lb);           \
    __builtin_amdgcn_s_setprio(1);                                           \
    _Pragma("unroll") for (int m = 0; m < 8; ++m)                            \
      _Pragma("unroll") for (int n = 0; n < 4; ++n)                          \
        acc[m][n] = __builtin_amdgcn_mfma_f32_16x16x32_bf16(                 \
            af[m], bg[n], acc[m][n], 0, 0, 0);                               \
    __builtin_amdgcn_s_setprio(0);                                           \
  } while (0)

__global__ __launch_bounds__(512, 4) void enc_gemm_bf16(
    const unsigned short* __restrict__ xh,  // [B][DDIM] bf16
    const unsigned short* __restrict__ wh,  // [FDIM][DDIM] bf16 (W^T)
    const float* __restrict__ bias,         // [FDIM]
    unsigned char* __restrict__ counts,     // [128 cb][B]
    uint2* __restrict__ slots,              // [B][128 cb][SLOTS]
    int B)
{
  __shared__ __align__(16) char smem[65536];  // 2 ring bufs x (A16K + B16K)
  const int tid = threadIdx.x;
  const int l = tid & 63;
  const int w = tid >> 6;                  // 8 waves
  const int wm = w >> 2, wn = w & 3;       // 2 x 4

  // XCD swizzle + panel-major decode (panel = 2 col-tiles = 512 cols = 2MB)
  const int nbx = gridDim.x;               // 64 col-tiles
  const int nby = gridDim.y;               // 32 row-tiles
  const int lin = blockIdx.y * nbx + blockIdx.x;
  const int nwg = nbx * nby;               // 2048, %8 == 0
  const int cpx = nwg >> 3;
  const int swz = (lin & 7) * cpx + (lin >> 3);
  const int pstripe = 2 * nby;
  const int p  = swz / pstripe;
  const int rm = swz % pstripe;
  const int row0 = (rm >> 1) * 256;
  const int col0 = (p * 2 + (rm & 1)) * 256;

  f32x4 acc[8][4] = {};

  // staging constants (verified XOR chunk swizzle, same as R3-R12)
  const int sr4 = tid >> 2;                          // 0..127
  const int sg  = (tid & 3) ^ ((sr4 >> 1) & 3);
  const size_t sgo = (size_t)sg * 16;
  const int wq = w * 1024;                           // wave-uniform LDS base
  const char* gx = (const char*)xh;
  const char* gw = (const char*)wh;

  // read-side lane base (verified): row (l&15), chunk (l>>4)^((l>>1)&3)
  const int lb  = (l & 15) * 64 + (((l >> 4) ^ ((l >> 1) & 3)) << 4);
  const int awm = wm * 8192;
  const int bwn = wn * 4096;

  // prologue: stage subtile 0
  STAGE(0);

  for (int s = 0; s < 63; ++s) KSTEP(s, 1);
  KSTEP(63, 0);

  // ---- epilogue: bias + relu + slot emit (256 rows x 2 col-blocks) ----
  __syncthreads();
  uint32_t* rcnt = (uint32_t*)smem;        // 512 counters: [lr][half]
  rcnt[tid] = 0;
  __syncthreads();

#pragma unroll
  for (int n = 0; n < 4; ++n) {
    const int col = col0 + wn * 64 + n * 16 + (l & 15);
    const float bb = bias[col];
    const int half = wn >> 1;
#pragma unroll
    for (int m = 0; m < 8; ++m) {
#pragma unroll
      for (int q = 0; q < 4; ++q) {
        const float zf = acc[m][n][q] + bb;   // > TCAND implies > 0 (relu)
        if (zf > TCAND) {
          const int lr = wm * 128 + m * 16 + (l >> 4) * 4 + q;
          const uint32_t ps = atomicAdd(&rcnt[lr * 2 + half], 1u);
          if (ps < SLOTS) {
            uint2 rec; rec.x = (uint32_t)col; rec.y = __float_as_uint(zf);
            slots[((size_t)(row0 + lr) * 128 + (col0 >> 7) + half) * SLOTS + ps]
                = rec;
          }
        }
      }
    }
  }
  __syncthreads();
  {
    const int lr = tid >> 1, half = tid & 1;
    uint32_t c = rcnt[tid];
    counts[(size_t)((col0 >> 7) + half) * B + row0 + lr] =
        (unsigned char)(c > 255u ? 255u : c);
  }
}

// ---------------------------------------------------------------------------
// Kernel 2: per-row exact top-64 from slot lists (verified R10-R12).
// ---------------------------------------------------------------------------
__global__ __launch_bounds__(256) void topk_kernel(
    const unsigned char* __restrict__ countsG,  // [128][B]
    const uint2* __restrict__ slotsG,           // [B][128][SLOTS]
    const float* __restrict__ x,                // [B][DDIM]
    const float* __restrict__ wtf,              // [FDIM][DDIM] f32 (W^T)
    const float* __restrict__ benc,             // [FDIM]
    int*   __restrict__ outIdx,                 // [B][TK]
    float* __restrict__ outVal,
    int B)
{
  const int row = blockIdx.x;
  const int tid = threadIdx.x;
  const float* xr = x + (size_t)row * DDIM;
  const uint2* slotsRow = slotsG + (size_t)row * 128 * SLOTS;

  __shared__ int    cnts[128];
  __shared__ int    sSum, sMax;
  __shared__ int    cIdx[CCAP];
  __shared__ float  cVal[CCAP];
  __shared__ short  sRank[CCAP];
  __shared__ unsigned char selF[CCAP];
  __shared__ int    cnt;
  __shared__ float  sV64;
  __shared__ int    wList[NCAP];
  __shared__ int    nW, winSel;
  __shared__ double dVals[NCAP];
  __shared__ int    keepFlag[NCAP];
  __shared__ double dred[256];

  if (tid == 0) { sSum = 0; sMax = 0; }
  __syncthreads();
  if (tid < 128) {
    int c = countsG[(size_t)tid * B + row];
    cnts[tid] = c;
    atomicAdd(&sSum, c);
    atomicMax(&sMax, c);
  }
  __syncthreads();
  const int total = sSum;
  bool useSlots = (total >= TK) && (total <= CCAP) && (sMax <= SLOTS);
  float Tlow = TCAND;
  int nc = 0;

  for (int pass = 0; pass < 2; ++pass) {
    if (tid == 0) cnt = 0;
    __syncthreads();
    if (useSlots) {
      for (int s = tid; s < 128 * SLOTS; s += 256) {
        const int cb = s / SLOTS, sl = s - cb * SLOTS;
        if (sl < cnts[cb]) {
          uint2 rec = slotsRow[s];
          int p = atomicAdd(&cnt, 1);
          cIdx[p] = (int)rec.x;
          cVal[p] = __uint_as_float(rec.y);
        }
      }
      __syncthreads();
      nc = cnt;
      __syncthreads();
    } else {
      float Tloc = Tlow;
      for (int attempt = 0; attempt < 16; ++attempt) {
        if (tid == 0) cnt = 0;
        __syncthreads();
        for (int f = tid; f < FDIM; f += 256) {
          const float* wr = wtf + (size_t)f * DDIM;
          float s = 0.f;
          for (int k = 0; k < DDIM; ++k) s = fmaf(xr[k], wr[k], s);
          const float zv = fmaxf(s + benc[f], 0.f);
          if (zv > Tloc) {
            int p = atomicAdd(&cnt, 1);
            if (p < CCAP) { cIdx[p] = f; cVal[p] = zv; }
          }
        }
        __syncthreads();
        nc = cnt;
        __syncthreads();
        if (nc >= TK && nc <= CCAP) break;
        Tloc += (nc > CCAP) ? 0.2f : -0.2f;
      }
      if (nc > CCAP) nc = CCAP;
    }

    for (int c = tid; c < nc; c += 256) {
      const float vi = cVal[c];
      const int   ii = cIdx[c];
      int rk = 0;
      for (int j = 0; j < nc; ++j) {
        const float vj = cVal[j];
        rk += (vj > vi) || (vj == vi && cIdx[j] < ii);
      }
      sRank[c] = (short)rk;
      selF[c] = (rk < TK) ? 1 : 0;
      if (rk == TK - 1) sV64 = vi;
    }
    __syncthreads();

    if (useSlots && sV64 - 0.02f <= TCAND) {
      useSlots = false;
      Tlow = sV64 - 0.04f;
      __syncthreads();
      continue;
    }
    break;
  }

  const float v64 = sV64;
  const float M = 0.02f;

  if (tid == 0) { nW = 0; winSel = 0; }
  __syncthreads();
  for (int c = tid; c < nc; c += 256) {
    if (fabsf(cVal[c] - v64) <= M) {
      int p = atomicAdd(&nW, 1);
      if (p < NCAP) wList[p] = c;
      if (sRank[c] < TK) atomicAdd(&winSel, 1);
    }
  }
  __syncthreads();
  const int nw = (nW < NCAP) ? nW : NCAP;

  if (nw > winSel) {
    for (int c = 0; c < nw; ++c) {
      const int f = cIdx[wList[c]];
      const float* wr = wtf + (size_t)f * DDIM;
      double part = 0.0;
      for (int k = tid; k < DDIM; k += 256)
        part += (double)xr[k] * (double)wr[k];
      dred[tid] = part;
      __syncthreads();
      for (int s = 128; s > 0; s >>= 1) {
        if (tid < s) dred[tid] += dred[tid + s];
        __syncthreads();
      }
      if (tid == 0) dVals[c] = dred[0] + (double)benc[f];
      __syncthreads();
    }
    if (tid == 0) {
      for (int c = 0; c < nw; ++c) keepFlag[c] = 0;
      int take = winSel < nw ? winSel : nw;
      for (int t = 0; t < take; ++t) {
        int best = -1;
        for (int c = 0; c < nw; ++c) {
          if (keepFlag[c]) continue;
          if (best < 0 || dVals[c] > dVals[best] ||
              (dVals[c] == dVals[best] && cIdx[wList[c]] < cIdx[wList[best]]))
            best = c;
        }
        keepFlag[best] = 1;
      }
      for (int c = 0; c < nw; ++c) selF[wList[c]] = (unsigned char)keepFlag[c];
    }
    __syncthreads();
  }

  for (int c = tid; c < nc; c += 256) {
    if (selF[c]) {
      const int myIdx = cIdx[c];
      int pos = 0;
      for (int j = 0; j < nc; ++j)
        pos += (selF[j] && cIdx[j] < myIdx);
      outIdx[(size_t)row * TK + pos] = myIdx;
      outVal[(size_t)row * TK + pos] = cVal[c];
    }
  }
}

// ---------------------------------------------------------------------------
// Kernel 3: decode, output-dim-sliced for L2 locality (verified R8-R12).
// ---------------------------------------------------------------------------
__global__ __launch_bounds__(128) void decode_kernel(
    const int*   __restrict__ idxL,
    const float* __restrict__ valL,
    const unsigned short* __restrict__ Wdb,  // [FDIM][DDIM] bf16
    const float* __restrict__ bd,
    float* __restrict__ out,
    int nrows)
{
  const unsigned bid = blockIdx.x;
  const int slice = bid / (unsigned)nrows;
  const int row   = bid % (unsigned)nrows;
  const int tid = threadIdx.x;
  const int d = slice * 128 + tid;

  __shared__ int   si[TK];
  __shared__ float sv[TK];
  if (tid < TK) {
    si[tid] = idxL[(size_t)row * TK + tid];
    sv[tid] = valL[(size_t)row * TK + tid];
  }
  __syncthreads();

  float a = bd[d];
#pragma unroll 8
  for (int t = 0; t < TK; ++t)
    a = fmaf(sv[t], bf2f(Wdb[(size_t)si[t] * DDIM + d]), a);
  out[(size_t)row * DDIM + d] = a;
}

// ---------------------------------------------------------------------------
extern "C" void kernel_launch(void* const* d_in, const int* in_sizes, int n_in,
                              void* d_out, int out_size, void* d_ws, size_t ws_size,
                              hipStream_t stream) {
  const float* x    = (const float*)d_in[0];
  const float* Wenc = (const float*)d_in[1];
  const float* benc = (const float*)d_in[2];
  const float* Wdec = (const float*)d_in[3];
  const float* bdec = (const float*)d_in[4];
  float* out = (float*)d_out;

  const int D = in_sizes[4];          // 2048
  const int B = in_sizes[0] / D;      // 8192

  // ws layout: idx | val | Wt_f32 | Wt_bf16 | x_h | Wd_b | counts | slots
  char* ws = (char*)d_ws;
  size_t off = 0;
  int*   idxL = (int*)ws;            off += (size_t)B * TK * 4;
  float* valL = (float*)(ws + off);  off += (size_t)B * TK * 4;
  off = (off + 255) & ~(size_t)255;
  float*          wtf = (float*)(ws + off);          off += (size_t)FDIM * DDIM * 4;
  unsigned short* wth = (unsigned short*)(ws + off); off += (size_t)FDIM * DDIM * 2;
  unsigned short* xh  = (unsigned short*)(ws + off); off += (size_t)B * DDIM * 2;
  unsigned short* wdb = (unsigned short*)(ws + off); off += (size_t)FDIM * DDIM * 2;
  off = (off + 255) & ~(size_t)255;
  unsigned char*  cntG = (unsigned char*)(ws + off); off += (size_t)128 * B;
  off = (off + 255) & ~(size_t)255;
  uint2*          slots = (uint2*)(ws + off);        off += (size_t)B * 128 * SLOTS * 8;

  conv_x<<<1024, 256, 0, stream>>>(x, xh, B * D / 4);
  conv_w<<<dim3(FDIM / 32, DDIM / 32), 256, 0, stream>>>(Wenc, wtf, wth);
  conv_wd<<<2048, 256, 0, stream>>>(Wdec, wdb, FDIM * DDIM / 4);

  dim3 g(FDIM / 256, B / 256);
  enc_gemm_bf16<<<g, 512, 0, stream>>>(xh, wth, benc, cntG, slots, B);
  topk_kernel<<<B, 256, 0, stream>>>(cntG, slots, x, wtf, benc,
                                     idxL, valL, B);
  decode_kernel<<<(DDIM / 128) * B, 128, 0, stream>>>(
      idxL, valL, wdb, bdec, out, B);
}

// Round 14
// 1257.348 us; speedup vs baseline: 4.6687x; 4.6687x over previous
//
#include <hip/hip_runtime.h>
#include <hip/hip_bf16.h>
#include <stdint.h>

#define TK 64
#define FDIM 16384
#define DDIM 2048
#define NCAP 128
#define CCAP 384
#define SLOTS 12
#define TCAND 2.25f

typedef __attribute__((ext_vector_type(8))) short bf16x8;
typedef __attribute__((ext_vector_type(4))) float f32x4;

#define GLL(g, p)                                                        \
  __builtin_amdgcn_global_load_lds(                                      \
      (const __attribute__((address_space(1))) uint32_t*)(g),            \
      (__attribute__((address_space(3))) uint32_t*)(p), 16, 0, 0)

__device__ __forceinline__ unsigned short f2bf(float a) {
  union { float f; uint32_t u; } p; p.f = a;
  uint32_t u = p.u;
  return (unsigned short)((u + 0x7FFFu + ((u >> 16) & 1u)) >> 16);
}
__device__ __forceinline__ float bf2f(unsigned short h) {
  union { uint32_t u; float f; } p; p.u = ((uint32_t)h) << 16; return p.f;
}

// ---------------------------------------------------------------------------
__global__ __launch_bounds__(256) void conv_x(
    const float* __restrict__ x, unsigned short* __restrict__ xh, int n4)
{
  int i = blockIdx.x * 256 + threadIdx.x;
  const int stride = gridDim.x * 256;
  for (; i < n4; i += stride) {
    float4 v = ((const float4*)x)[i];
    ushort4 h;
    h.x = f2bf(v.x); h.y = f2bf(v.y); h.z = f2bf(v.z); h.w = f2bf(v.w);
    ((ushort4*)xh)[i] = h;
  }
}

// ---------------------------------------------------------------------------
__global__ __launch_bounds__(256) void conv_w(
    const float* __restrict__ W, float* __restrict__ wtf,
    unsigned short* __restrict__ wh)
{
  __shared__ float t[32][33];
  const int f0 = blockIdx.x * 32, d0 = blockIdx.y * 32;
  const int tr = threadIdx.x >> 3;
  const int tc = (threadIdx.x & 7) * 4;
  float4 v = *(const float4*)(W + (size_t)(d0 + tr) * FDIM + f0 + tc);
  t[tr][tc + 0] = v.x; t[tr][tc + 1] = v.y;
  t[tr][tc + 2] = v.z; t[tr][tc + 3] = v.w;
  __syncthreads();
  float a0 = t[tc + 0][tr], a1 = t[tc + 1][tr];
  float a2 = t[tc + 2][tr], a3 = t[tc + 3][tr];
  *(float4*)(wtf + (size_t)(f0 + tr) * DDIM + d0 + tc) =
      make_float4(a0, a1, a2, a3);
  ushort4 h;
  h.x = f2bf(a0); h.y = f2bf(a1); h.z = f2bf(a2); h.w = f2bf(a3);
  *(ushort4*)(wh + (size_t)(f0 + tr) * DDIM + d0 + tc) = h;
}

// ---------------------------------------------------------------------------
__global__ __launch_bounds__(256) void conv_wd(
    const float* __restrict__ W, unsigned short* __restrict__ Wb, int n4)
{
  int i = blockIdx.x * 256 + threadIdx.x;
  const int stride = gridDim.x * 256;
  for (; i < n4; i += stride) {
    float4 v = ((const float4*)W)[i];
    ushort4 h;
    h.x = f2bf(v.x); h.y = f2bf(v.y); h.z = f2bf(v.z); h.w = f2bf(v.w);
    ((ushort4*)Wb)[i] = h;
  }
}

// ---------------------------------------------------------------------------
// Kernel 1: encode GEMM, 256x256 tile, 8 waves (2Mx4N), BK=32, double-buffer
// LDS (64 KB) for 2-blocks/CU co-residency. R14: launch_bounds(512,2) —
// R13's (512,4) capped VGPR at 64 and spilled the 128-reg accumulator to
// scratch (10 GB FETCH, MfmaUtil 4%). (512,2) gives VGPR~116 <= 128, so
// 2 blocks/CU co-reside via HW occupancy (LDS 64KB, VGPR 116 -> 4 waves/SIMD).
// ---------------------------------------------------------------------------
#define STAGE(T) do {                                                        \
    const int rb_ = (T) & 1;                                                 \
    const size_t ko_ = (size_t)(T) * 64;                                     \
    const size_t rA0 = (size_t)(row0 + sr4) * 4096 + ko_ + sgo;              \
    GLL(gx + rA0, smem + rb_ * 32768 + wq);                                  \
    const size_t rB0 = (size_t)(col0 + sr4) * 4096 + ko_ + sgo;              \
    GLL(gw + rB0, smem + rb_ * 32768 + 16384 + wq);                          \
    const size_t rA1 = (size_t)(row0 + 128 + sr4) * 4096 + ko_ + sgo;        \
    GLL(gx + rA1, smem + rb_ * 32768 + 8192 + wq);                           \
    const size_t rB1 = (size_t)(col0 + 128 + sr4) * 4096 + ko_ + sgo;        \
    GLL(gw + rB1, smem + rb_ * 32768 + 16384 + 8192 + wq);                   \
  } while (0)

#define KSTEP(S, DOSTAGE) do {                                               \
    asm volatile("s_waitcnt vmcnt(0)" ::: "memory");                         \
    __builtin_amdgcn_s_barrier();                                            \
    if (DOSTAGE) STAGE((S) + 1);                                             \
    const char* tb_ = smem + ((S) & 1) * 32768;                              \
    bf16x8 af[8], bg[4];                                                     \
    _Pragma("unroll") for (int m = 0; m < 8; ++m)                            \
      af[m] = *(const bf16x8*)(tb_ + awm + m * 1024 + lb);                   \
    _Pragma("unroll") for (int n = 0; n < 4; ++n)                            \
      bg[n] = *(const bf16x8*)(tb_ + 16384 + bwn + n * 1024 + lb);           \
    __builtin_amdgcn_s_setprio(1);                                           \
    _Pragma("unroll") for (int m = 0; m < 8; ++m)                            \
      _Pragma("unroll") for (int n = 0; n < 4; ++n)                          \
        acc[m][n] = __builtin_amdgcn_mfma_f32_16x16x32_bf16(                 \
            af[m], bg[n], acc[m][n], 0, 0, 0);                               \
    __builtin_amdgcn_s_setprio(0);                                           \
  } while (0)

__global__ __launch_bounds__(512, 2) void enc_gemm_bf16(
    const unsigned short* __restrict__ xh,  // [B][DDIM] bf16
    const unsigned short* __restrict__ wh,  // [FDIM][DDIM] bf16 (W^T)
    const float* __restrict__ bias,         // [FDIM]
    unsigned char* __restrict__ counts,     // [128 cb][B]
    uint2* __restrict__ slots,              // [B][128 cb][SLOTS]
    int B)
{
  __shared__ __align__(16) char smem[65536];  // 2 bufs x (A16K + B16K)
  const int tid = threadIdx.x;
  const int l = tid & 63;
  const int w = tid >> 6;                  // 8 waves
  const int wm = w >> 2, wn = w & 3;       // 2 x 4

  // XCD swizzle + panel-major decode (panel = 2 col-tiles = 512 cols = 2MB)
  const int nbx = gridDim.x;               // 64 col-tiles
  const int nby = gridDim.y;               // 32 row-tiles
  const int lin = blockIdx.y * nbx + blockIdx.x;
  const int nwg = nbx * nby;               // 2048, %8 == 0
  const int cpx = nwg >> 3;
  const int swz = (lin & 7) * cpx + (lin >> 3);
  const int pstripe = 2 * nby;
  const int p  = swz / pstripe;
  const int rm = swz % pstripe;
  const int row0 = (rm >> 1) * 256;
  const int col0 = (p * 2 + (rm & 1)) * 256;

  f32x4 acc[8][4] = {};

  // staging constants (verified XOR chunk swizzle, same as R3-R13)
  const int sr4 = tid >> 2;                          // 0..127
  const int sg  = (tid & 3) ^ ((sr4 >> 1) & 3);
  const size_t sgo = (size_t)sg * 16;
  const int wq = w * 1024;                           // wave-uniform LDS base
  const char* gx = (const char*)xh;
  const char* gw = (const char*)wh;

  // read-side lane base (verified): row (l&15), chunk (l>>4)^((l>>1)&3)
  const int lb  = (l & 15) * 64 + (((l >> 4) ^ ((l >> 1) & 3)) << 4);
  const int awm = wm * 8192;
  const int bwn = wn * 4096;

  // prologue: stage subtile 0
  STAGE(0);

  for (int s = 0; s < 63; ++s) KSTEP(s, 1);
  KSTEP(63, 0);

  // ---- epilogue: bias + relu + slot emit (256 rows x 2 col-blocks) ----
  __syncthreads();
  uint32_t* rcnt = (uint32_t*)smem;        // 512 counters: [lr][half]
  rcnt[tid] = 0;
  __syncthreads();

#pragma unroll
  for (int n = 0; n < 4; ++n) {
    const int col = col0 + wn * 64 + n * 16 + (l & 15);
    const float bb = bias[col];
    const int half = wn >> 1;
#pragma unroll
    for (int m = 0; m < 8; ++m) {
#pragma unroll
      for (int q = 0; q < 4; ++q) {
        const float zf = acc[m][n][q] + bb;   // > TCAND implies > 0 (relu)
        if (zf > TCAND) {
          const int lr = wm * 128 + m * 16 + (l >> 4) * 4 + q;
          const uint32_t ps = atomicAdd(&rcnt[lr * 2 + half], 1u);
          if (ps < SLOTS) {
            uint2 rec; rec.x = (uint32_t)col; rec.y = __float_as_uint(zf);
            slots[((size_t)(row0 + lr) * 128 + (col0 >> 7) + half) * SLOTS + ps]
                = rec;
          }
        }
      }
    }
  }
  __syncthreads();
  {
    const int lr = tid >> 1, half = tid & 1;
    uint32_t c = rcnt[tid];
    counts[(size_t)((col0 >> 7) + half) * B + row0 + lr] =
        (unsigned char)(c > 255u ? 255u : c);
  }
}

// ---------------------------------------------------------------------------
// Kernel 2: per-row exact top-64 from slot lists (verified R10-R13).
// ---------------------------------------------------------------------------
__global__ __launch_bounds__(256) void topk_kernel(
    const unsigned char* __restrict__ countsG,  // [128][B]
    const uint2* __restrict__ slotsG,           // [B][128][SLOTS]
    const float* __restrict__ x,                // [B][DDIM]
    const float* __restrict__ wtf,              // [FDIM][DDIM] f32 (W^T)
    const float* __restrict__ benc,             // [FDIM]
    int*   __restrict__ outIdx,                 // [B][TK]
    float* __restrict__ outVal,
    int B)
{
  const int row = blockIdx.x;
  const int tid = threadIdx.x;
  const float* xr = x + (size_t)row * DDIM;
  const uint2* slotsRow = slotsG + (size_t)row * 128 * SLOTS;

  __shared__ int    cnts[128];
  __shared__ int    sSum, sMax;
  __shared__ int    cIdx[CCAP];
  __shared__ float  cVal[CCAP];
  __shared__ short  sRank[CCAP];
  __shared__ unsigned char selF[CCAP];
  __shared__ int    cnt;
  __shared__ float  sV64;
  __shared__ int    wList[NCAP];
  __shared__ int    nW, winSel;
  __shared__ double dVals[NCAP];
  __shared__ int    keepFlag[NCAP];
  __shared__ double dred[256];

  if (tid == 0) { sSum = 0; sMax = 0; }
  __syncthreads();
  if (tid < 128) {
    int c = countsG[(size_t)tid * B + row];
    cnts[tid] = c;
    atomicAdd(&sSum, c);
    atomicMax(&sMax, c);
  }
  __syncthreads();
  const int total = sSum;
  bool useSlots = (total >= TK) && (total <= CCAP) && (sMax <= SLOTS);
  float Tlow = TCAND;
  int nc = 0;

  for (int pass = 0; pass < 2; ++pass) {
    if (tid == 0) cnt = 0;
    __syncthreads();
    if (useSlots) {
      for (int s = tid; s < 128 * SLOTS; s += 256) {
        const int cb = s / SLOTS, sl = s - cb * SLOTS;
        if (sl < cnts[cb]) {
          uint2 rec = slotsRow[s];
          int p = atomicAdd(&cnt, 1);
          cIdx[p] = (int)rec.x;
          cVal[p] = __uint_as_float(rec.y);
        }
      }
      __syncthreads();
      nc = cnt;
      __syncthreads();
    } else {
      float Tloc = Tlow;
      for (int attempt = 0; attempt < 16; ++attempt) {
        if (tid == 0) cnt = 0;
        __syncthreads();
        for (int f = tid; f < FDIM; f += 256) {
          const float* wr = wtf + (size_t)f * DDIM;
          float s = 0.f;
          for (int k = 0; k < DDIM; ++k) s = fmaf(xr[k], wr[k], s);
          const float zv = fmaxf(s + benc[f], 0.f);
          if (zv > Tloc) {
            int p = atomicAdd(&cnt, 1);
            if (p < CCAP) { cIdx[p] = f; cVal[p] = zv; }
          }
        }
        __syncthreads();
        nc = cnt;
        __syncthreads();
        if (nc >= TK && nc <= CCAP) break;
        Tloc += (nc > CCAP) ? 0.2f : -0.2f;
      }
      if (nc > CCAP) nc = CCAP;
    }

    for (int c = tid; c < nc; c += 256) {
      const float vi = cVal[c];
      const int   ii = cIdx[c];
      int rk = 0;
      for (int j = 0; j < nc; ++j) {
        const float vj = cVal[j];
        rk += (vj > vi) || (vj == vi && cIdx[j] < ii);
      }
      sRank[c] = (short)rk;
      selF[c] = (rk < TK) ? 1 : 0;
      if (rk == TK - 1) sV64 = vi;
    }
    __syncthreads();

    if (useSlots && sV64 - 0.02f <= TCAND) {
      useSlots = false;
      Tlow = sV64 - 0.04f;
      __syncthreads();
      continue;
    }
    break;
  }

  const float v64 = sV64;
  const float M = 0.02f;

  if (tid == 0) { nW = 0; winSel = 0; }
  __syncthreads();
  for (int c = tid; c < nc; c += 256) {
    if (fabsf(cVal[c] - v64) <= M) {
      int p = atomicAdd(&nW, 1);
      if (p < NCAP) wList[p] = c;
      if (sRank[c] < TK) atomicAdd(&winSel, 1);
    }
  }
  __syncthreads();
  const int nw = (nW < NCAP) ? nW : NCAP;

  if (nw > winSel) {
    for (int c = 0; c < nw; ++c) {
      const int f = cIdx[wList[c]];
      const float* wr = wtf + (size_t)f * DDIM;
      double part = 0.0;
      for (int k = tid; k < DDIM; k += 256)
        part += (double)xr[k] * (double)wr[k];
      dred[tid] = part;
      __syncthreads();
      for (int s = 128; s > 0; s >>= 1) {
        if (tid < s) dred[tid] += dred[tid + s];
        __syncthreads();
      }
      if (tid == 0) dVals[c] = dred[0] + (double)benc[f];
      __syncthreads();
    }
    if (tid == 0) {
      for (int c = 0; c < nw; ++c) keepFlag[c] = 0;
      int take = winSel < nw ? winSel : nw;
      for (int t = 0; t < take; ++t) {
        int best = -1;
        for (int c = 0; c < nw; ++c) {
          if (keepFlag[c]) continue;
          if (best < 0 || dVals[c] > dVals[best] ||
              (dVals[c] == dVals[best] && cIdx[wList[c]] < cIdx[wList[best]]))
            best = c;
        }
        keepFlag[best] = 1;
      }
      for (int c = 0; c < nw; ++c) selF[wList[c]] = (unsigned char)keepFlag[c];
    }
    __syncthreads();
  }

  for (int c = tid; c < nc; c += 256) {
    if (selF[c]) {
      const int myIdx = cIdx[c];
      int pos = 0;
      for (int j = 0; j < nc; ++j)
        pos += (selF[j] && cIdx[j] < myIdx);
      outIdx[(size_t)row * TK + pos] = myIdx;
      outVal[(size_t)row * TK + pos] = cVal[c];
    }
  }
}

// ---------------------------------------------------------------------------
// Kernel 3: decode, output-dim-sliced for L2 locality (verified R8-R13).
// ---------------------------------------------------------------------------
__global__ __launch_bounds__(128) void decode_kernel(
    const int*   __restrict__ idxL,
    const float* __restrict__ valL,
    const unsigned short* __restrict__ Wdb,  // [FDIM][DDIM] bf16
    const float* __restrict__ bd,
    float* __restrict__ out,
    int nrows)
{
  const unsigned bid = blockIdx.x;
  const int slice = bid / (unsigned)nrows;
  const int row   = bid % (unsigned)nrows;
  const int tid = threadIdx.x;
  const int d = slice * 128 + tid;

  __shared__ int   si[TK];
  __shared__ float sv[TK];
  if (tid < TK) {
    si[tid] = idxL[(size_t)row * TK + tid];
    sv[tid] = valL[(size_t)row * TK + tid];
  }
  __syncthreads();

  float a = bd[d];
#pragma unroll 8
  for (int t = 0; t < TK; ++t)
    a = fmaf(sv[t], bf2f(Wdb[(size_t)si[t] * DDIM + d]), a);
  out[(size_t)row * DDIM + d] = a;
}

// ---------------------------------------------------------------------------
extern "C" void kernel_launch(void* const* d_in, const int* in_sizes, int n_in,
                              void* d_out, int out_size, void* d_ws, size_t ws_size,
                              hipStream_t stream) {
  const float* x    = (const float*)d_in[0];
  const float* Wenc = (const float*)d_in[1];
  const float* benc = (const float*)d_in[2];
  const float* Wdec = (const float*)d_in[3];
  const float* bdec = (const float*)d_in[4];
  float* out = (float*)d_out;

  const int D = in_sizes[4];          // 2048
  const int B = in_sizes[0] / D;      // 8192

  // ws layout: idx | val | Wt_f32 | Wt_bf16 | x_h | Wd_b | counts | slots
  char* ws = (char*)d_ws;
  size_t off = 0;
  int*   idxL = (int*)ws;            off += (size_t)B * TK * 4;
  float* valL = (float*)(ws + off);  off += (size_t)B * TK * 4;
  off = (off + 255) & ~(size_t)255;
  float*          wtf = (float*)(ws + off);          off += (size_t)FDIM * DDIM * 4;
  unsigned short* wth = (unsigned short*)(ws + off); off += (size_t)FDIM * DDIM * 2;
  unsigned short* xh  = (unsigned short*)(ws + off); off += (size_t)B * DDIM * 2;
  unsigned short* wdb = (unsigned short*)(ws + off); off += (size_t)FDIM * DDIM * 2;
  off = (off + 255) & ~(size_t)255;
  unsigned char*  cntG = (unsigned char*)(ws + off); off += (size_t)128 * B;
  off = (off + 255) & ~(size_t)255;
  uint2*          slots = (uint2*)(ws + off);        off += (size_t)B * 128 * SLOTS * 8;

  conv_x<<<1024, 256, 0, stream>>>(x, xh, B * D / 4);
  conv_w<<<dim3(FDIM / 32, DDIM / 32), 256, 0, stream>>>(Wenc, wtf, wth);
  conv_wd<<<2048, 256, 0, stream>>>(Wdec, wdb, FDIM * DDIM / 4);

  dim3 g(FDIM / 256, B / 256);
  enc_gemm_bf16<<<g, 512, 0, stream>>>(xh, wth, benc, cntG, slots, B);
  topk_kernel<<<B, 256, 0, stream>>>(cntG, slots, x, wtf, benc,
                                     idxL, valL, B);
  decode_kernel<<<(DDIM / 128) * B, 128, 0, stream>>>(
      idxL, valL, wdb, bdec, out, B);
}

// Round 15
// 1178.901 us; speedup vs baseline: 4.9793x; 1.0665x over previous
//
#include <hip/hip_runtime.h>
#include <hip/hip_bf16.h>
#include <stdint.h>

#define TK 64
#define FDIM 16384
#define DDIM 2048
#define NCAP 128
#define CCAP 384
#define SLOTS 12
#define TCAND 2.25f

typedef __attribute__((ext_vector_type(8))) short bf16x8;
typedef __attribute__((ext_vector_type(4))) float f32x4;

#define GLL(g, p)                                                        \
  __builtin_amdgcn_global_load_lds(                                      \
      (const __attribute__((address_space(1))) uint32_t*)(g),            \
      (__attribute__((address_space(3))) uint32_t*)(p), 16, 0, 0)

__device__ __forceinline__ unsigned short f2bf(float a) {
  union { float f; uint32_t u; } p; p.f = a;
  uint32_t u = p.u;
  return (unsigned short)((u + 0x7FFFu + ((u >> 16) & 1u)) >> 16);
}
__device__ __forceinline__ float bf2f(unsigned short h) {
  union { uint32_t u; float f; } p; p.u = ((uint32_t)h) << 16; return p.f;
}

// ---------------------------------------------------------------------------
__global__ __launch_bounds__(256) void conv_x(
    const float* __restrict__ x, unsigned short* __restrict__ xh, int n4)
{
  int i = blockIdx.x * 256 + threadIdx.x;
  const int stride = gridDim.x * 256;
  for (; i < n4; i += stride) {
    float4 v = ((const float4*)x)[i];
    ushort4 h;
    h.x = f2bf(v.x); h.y = f2bf(v.y); h.z = f2bf(v.z); h.w = f2bf(v.w);
    ((ushort4*)xh)[i] = h;
  }
}

// ---------------------------------------------------------------------------
__global__ __launch_bounds__(256) void conv_w(
    const float* __restrict__ W, float* __restrict__ wtf,
    unsigned short* __restrict__ wh)
{
  __shared__ float t[32][33];
  const int f0 = blockIdx.x * 32, d0 = blockIdx.y * 32;
  const int tr = threadIdx.x >> 3;
  const int tc = (threadIdx.x & 7) * 4;
  float4 v = *(const float4*)(W + (size_t)(d0 + tr) * FDIM + f0 + tc);
  t[tr][tc + 0] = v.x; t[tr][tc + 1] = v.y;
  t[tr][tc + 2] = v.z; t[tr][tc + 3] = v.w;
  __syncthreads();
  float a0 = t[tc + 0][tr], a1 = t[tc + 1][tr];
  float a2 = t[tc + 2][tr], a3 = t[tc + 3][tr];
  *(float4*)(wtf + (size_t)(f0 + tr) * DDIM + d0 + tc) =
      make_float4(a0, a1, a2, a3);
  ushort4 h;
  h.x = f2bf(a0); h.y = f2bf(a1); h.z = f2bf(a2); h.w = f2bf(a3);
  *(ushort4*)(wh + (size_t)(f0 + tr) * DDIM + d0 + tc) = h;
}

// ---------------------------------------------------------------------------
__global__ __launch_bounds__(256) void conv_wd(
    const float* __restrict__ W, unsigned short* __restrict__ Wb, int n4)
{
  int i = blockIdx.x * 256 + threadIdx.x;
  const int stride = gridDim.x * 256;
  for (; i < n4; i += stride) {
    float4 v = ((const float4*)W)[i];
    ushort4 h;
    h.x = f2bf(v.x); h.y = f2bf(v.y); h.z = f2bf(v.z); h.w = f2bf(v.w);
    ((ushort4*)Wb)[i] = h;
  }
}

// ---------------------------------------------------------------------------
// Kernel 1: encode GEMM — EXACT R12 version (best measured: 574 us, 951 TF,
// MfmaUtil 44%). 256x256 tile, 8 waves, BK=32 subtile ring of 4 LDS bufs,
// counted vmcnt(8), one raw s_barrier per K-step, XOR chunk swizzle,
// panel-major XCD order, slot-emit epilogue. DO NOT TOUCH.
// ---------------------------------------------------------------------------
#define STAGE(T) do {                                                        \
    const int rb_ = (T) & 3;                                                 \
    const size_t ko_ = (size_t)(T) * 64;                                     \
    const size_t rA0 = (size_t)(row0 + sr4) * 4096 + ko_ + sgo;              \
    GLL(gx + rA0, smem + rb_ * 32768 + wq);                                  \
    const size_t rB0 = (size_t)(col0 + sr4) * 4096 + ko_ + sgo;              \
    GLL(gw + rB0, smem + rb_ * 32768 + 16384 + wq);                          \
    const size_t rA1 = (size_t)(row0 + 128 + sr4) * 4096 + ko_ + sgo;        \
    GLL(gx + rA1, smem + rb_ * 32768 + 8192 + wq);                           \
    const size_t rB1 = (size_t)(col0 + 128 + sr4) * 4096 + ko_ + sgo;        \
    GLL(gw + rB1, smem + rb_ * 32768 + 16384 + 8192 + wq);                   \
  } while (0)

#define KSTEP(S, VMC, DOSTAGE) do {                                          \
    asm volatile("s_waitcnt vmcnt(" #VMC ")" ::: "memory");                  \
    __builtin_amdgcn_s_barrier();                                            \
    const char* tb_ = smem + ((S) & 3) * 32768;                              \
    bf16x8 af[8], bg[4];                                                     \
    _Pragma("unroll") for (int m = 0; m < 8; ++m)                            \
      af[m] = *(const bf16x8*)(tb_ + awm + m * 1024 + lb);                   \
    _Pragma("unroll") for (int n = 0; n < 4; ++n)                            \
      bg[n] = *(const bf16x8*)(tb_ + 16384 + bwn + n * 1024 + lb);           \
    if (DOSTAGE) STAGE((S) + 3);                                             \
    __builtin_amdgcn_s_setprio(1);                                           \
    _Pragma("unroll") for (int m = 0; m < 8; ++m)                            \
      _Pragma("unroll") for (int n = 0; n < 4; ++n)                          \
        acc[m][n] = __builtin_amdgcn_mfma_f32_16x16x32_bf16(                 \
            af[m], bg[n], acc[m][n], 0, 0, 0);                               \
    __builtin_amdgcn_s_setprio(0);                                           \
  } while (0)

__global__ __launch_bounds__(512, 2) void enc_gemm_bf16(
    const unsigned short* __restrict__ xh,  // [B][DDIM] bf16
    const unsigned short* __restrict__ wh,  // [FDIM][DDIM] bf16 (W^T)
    const float* __restrict__ bias,         // [FDIM]
    unsigned char* __restrict__ counts,     // [128 cb][B]
    uint2* __restrict__ slots,              // [B][128 cb][SLOTS]
    int B)
{
  __shared__ __align__(16) char smem[131072];  // 4 ring bufs x (A16K + B16K)
  const int tid = threadIdx.x;
  const int l = tid & 63;
  const int w = tid >> 6;                  // 8 waves
  const int wm = w >> 2, wn = w & 3;       // 2 x 4

  // XCD swizzle + panel-major decode (panel = 2 col-tiles = 512 cols = 2MB)
  const int nbx = gridDim.x;               // 64 col-tiles
  const int nby = gridDim.y;               // 32 row-tiles
  const int lin = blockIdx.y * nbx + blockIdx.x;
  const int nwg = nbx * nby;               // 2048, %8 == 0
  const int cpx = nwg >> 3;
  const int swz = (lin & 7) * cpx + (lin >> 3);
  const int pstripe = 2 * nby;
  const int p  = swz / pstripe;
  const int rm = swz % pstripe;
  const int row0 = (rm >> 1) * 256;
  const int col0 = (p * 2 + (rm & 1)) * 256;

  f32x4 acc[8][4] = {};

  const int sr4 = tid >> 2;                          // 0..127
  const int sg  = (tid & 3) ^ ((sr4 >> 1) & 3);
  const size_t sgo = (size_t)sg * 16;
  const int wq = w * 1024;                           // wave-uniform LDS base
  const char* gx = (const char*)xh;
  const char* gw = (const char*)wh;

  const int lb  = (l & 15) * 64 + (((l >> 4) ^ ((l >> 1) & 3)) << 4);
  const int awm = wm * 8192;
  const int bwn = wn * 4096;

  STAGE(0); STAGE(1); STAGE(2);

  for (int s = 0; s < 61; ++s) KSTEP(s, 8, 1);
  KSTEP(61, 8, 0);
  KSTEP(62, 4, 0);
  KSTEP(63, 0, 0);

  // ---- epilogue: bias + relu + slot emit (256 rows x 2 col-blocks) ----
  __syncthreads();
  uint32_t* rcnt = (uint32_t*)smem;        // 512 counters: [lr][half]
  rcnt[tid] = 0;
  __syncthreads();

#pragma unroll
  for (int n = 0; n < 4; ++n) {
    const int col = col0 + wn * 64 + n * 16 + (l & 15);
    const float bb = bias[col];
    const int half = wn >> 1;
#pragma unroll
    for (int m = 0; m < 8; ++m) {
#pragma unroll
      for (int q = 0; q < 4; ++q) {
        const float zf = acc[m][n][q] + bb;   // > TCAND implies > 0 (relu)
        if (zf > TCAND) {
          const int lr = wm * 128 + m * 16 + (l >> 4) * 4 + q;
          const uint32_t ps = atomicAdd(&rcnt[lr * 2 + half], 1u);
          if (ps < SLOTS) {
            uint2 rec; rec.x = (uint32_t)col; rec.y = __float_as_uint(zf);
            slots[((size_t)(row0 + lr) * 128 + (col0 >> 7) + half) * SLOTS + ps]
                = rec;
          }
        }
      }
    }
  }
  __syncthreads();
  {
    const int lr = tid >> 1, half = tid & 1;
    uint32_t c = rcnt[tid];
    counts[(size_t)((col0 >> 7) + half) * B + row0 + lr] =
        (unsigned char)(c > 255u ? 255u : c);
  }
}

// ---------------------------------------------------------------------------
// Kernel 2: per-row exact top-64 from slot lists (verified R10-R14).
// ---------------------------------------------------------------------------
__global__ __launch_bounds__(256) void topk_kernel(
    const unsigned char* __restrict__ countsG,  // [128][B]
    const uint2* __restrict__ slotsG,           // [B][128][SLOTS]
    const float* __restrict__ x,                // [B][DDIM]
    const float* __restrict__ wtf,              // [FDIM][DDIM] f32 (W^T)
    const float* __restrict__ benc,             // [FDIM]
    int*   __restrict__ outIdx,                 // [B][TK]
    float* __restrict__ outVal,
    int B)
{
  const int row = blockIdx.x;
  const int tid = threadIdx.x;
  const float* xr = x + (size_t)row * DDIM;
  const uint2* slotsRow = slotsG + (size_t)row * 128 * SLOTS;

  __shared__ int    cnts[128];
  __shared__ int    sSum, sMax;
  __shared__ int    cIdx[CCAP];
  __shared__ float  cVal[CCAP];
  __shared__ short  sRank[CCAP];
  __shared__ unsigned char selF[CCAP];
  __shared__ int    cnt;
  __shared__ float  sV64;
  __shared__ int    wList[NCAP];
  __shared__ int    nW, winSel;
  __shared__ double dVals[NCAP];
  __shared__ int    keepFlag[NCAP];
  __shared__ double dred[256];

  if (tid == 0) { sSum = 0; sMax = 0; }
  __syncthreads();
  if (tid < 128) {
    int c = countsG[(size_t)tid * B + row];
    cnts[tid] = c;
    atomicAdd(&sSum, c);
    atomicMax(&sMax, c);
  }
  __syncthreads();
  const int total = sSum;
  bool useSlots = (total >= TK) && (total <= CCAP) && (sMax <= SLOTS);
  float Tlow = TCAND;
  int nc = 0;

  for (int pass = 0; pass < 2; ++pass) {
    if (tid == 0) cnt = 0;
    __syncthreads();
    if (useSlots) {
      for (int s = tid; s < 128 * SLOTS; s += 256) {
        const int cb = s / SLOTS, sl = s - cb * SLOTS;
        if (sl < cnts[cb]) {
          uint2 rec = slotsRow[s];
          int p = atomicAdd(&cnt, 1);
          cIdx[p] = (int)rec.x;
          cVal[p] = __uint_as_float(rec.y);
        }
      }
      __syncthreads();
      nc = cnt;
      __syncthreads();
    } else {
      float Tloc = Tlow;
      for (int attempt = 0; attempt < 16; ++attempt) {
        if (tid == 0) cnt = 0;
        __syncthreads();
        for (int f = tid; f < FDIM; f += 256) {
          const float* wr = wtf + (size_t)f * DDIM;
          float s = 0.f;
          for (int k = 0; k < DDIM; ++k) s = fmaf(xr[k], wr[k], s);
          const float zv = fmaxf(s + benc[f], 0.f);
          if (zv > Tloc) {
            int p = atomicAdd(&cnt, 1);
            if (p < CCAP) { cIdx[p] = f; cVal[p] = zv; }
          }
        }
        __syncthreads();
        nc = cnt;
        __syncthreads();
        if (nc >= TK && nc <= CCAP) break;
        Tloc += (nc > CCAP) ? 0.2f : -0.2f;
      }
      if (nc > CCAP) nc = CCAP;
    }

    for (int c = tid; c < nc; c += 256) {
      const float vi = cVal[c];
      const int   ii = cIdx[c];
      int rk = 0;
      for (int j = 0; j < nc; ++j) {
        const float vj = cVal[j];
        rk += (vj > vi) || (vj == vi && cIdx[j] < ii);
      }
      sRank[c] = (short)rk;
      selF[c] = (rk < TK) ? 1 : 0;
      if (rk == TK - 1) sV64 = vi;
    }
    __syncthreads();

    if (useSlots && sV64 - 0.02f <= TCAND) {
      useSlots = false;
      Tlow = sV64 - 0.04f;
      __syncthreads();
      continue;
    }
    break;
  }

  const float v64 = sV64;
  const float M = 0.02f;

  if (tid == 0) { nW = 0; winSel = 0; }
  __syncthreads();
  for (int c = tid; c < nc; c += 256) {
    if (fabsf(cVal[c] - v64) <= M) {
      int p = atomicAdd(&nW, 1);
      if (p < NCAP) wList[p] = c;
      if (sRank[c] < TK) atomicAdd(&winSel, 1);
    }
  }
  __syncthreads();
  const int nw = (nW < NCAP) ? nW : NCAP;

  if (nw > winSel) {
    for (int c = 0; c < nw; ++c) {
      const int f = cIdx[wList[c]];
      const float* wr = wtf + (size_t)f * DDIM;
      double part = 0.0;
      for (int k = tid; k < DDIM; k += 256)
        part += (double)xr[k] * (double)wr[k];
      dred[tid] = part;
      __syncthreads();
      for (int s = 128; s > 0; s >>= 1) {
        if (tid < s) dred[tid] += dred[tid + s];
        __syncthreads();
      }
      if (tid == 0) dVals[c] = dred[0] + (double)benc[f];
      __syncthreads();
    }
    if (tid == 0) {
      for (int c = 0; c < nw; ++c) keepFlag[c] = 0;
      int take = winSel < nw ? winSel : nw;
      for (int t = 0; t < take; ++t) {
        int best = -1;
        for (int c = 0; c < nw; ++c) {
          if (keepFlag[c]) continue;
          if (best < 0 || dVals[c] > dVals[best] ||
              (dVals[c] == dVals[best] && cIdx[wList[c]] < cIdx[wList[best]]))
            best = c;
        }
        keepFlag[best] = 1;
      }
      for (int c = 0; c < nw; ++c) selF[wList[c]] = (unsigned char)keepFlag[c];
    }
    __syncthreads();
  }

  for (int c = tid; c < nc; c += 256) {
    if (selF[c]) {
      const int myIdx = cIdx[c];
      int pos = 0;
      for (int j = 0; j < nc; ++j)
        pos += (selF[j] && cIdx[j] < myIdx);
      outIdx[(size_t)row * TK + pos] = myIdx;
      outVal[(size_t)row * TK + pos] = cVal[c];
    }
  }
}

// ---------------------------------------------------------------------------
// Kernel 3: decode, slice-major L2 blocking (verified R8) + R15 vectorize:
// 4 rows/block x 128-dim slice; 128 threads = 4 rows x 32 lanes; each lane
// gathers ushort4 (8B) instead of scalar 2B; si/sv amortized over 4 rows;
// 4x fewer blocks (32768). W_dec slice (4.2 MB) stays L2-resident.
// ---------------------------------------------------------------------------
__global__ __launch_bounds__(128) void decode_kernel(
    const int*   __restrict__ idxL,
    const float* __restrict__ valL,
    const unsigned short* __restrict__ Wdb,  // [FDIM][DDIM] bf16
    const float* __restrict__ bd,
    float* __restrict__ out,
    int nrowg)                               // B/4 row-groups
{
  const unsigned bid = blockIdx.x;
  const int slice = bid / (unsigned)nrowg;   // slice-major
  const int rg    = bid % (unsigned)nrowg;
  const int row0  = rg * 4;
  const int tid = threadIdx.x;
  const int r  = tid >> 5;                   // row within group (0..3)
  const int d  = slice * 128 + (tid & 31) * 4;

  __shared__ int   si[4][TK];
  __shared__ float sv[4][TK];
  for (int i = tid; i < 4 * TK; i += 128) {
    const int rr = i >> 6, t = i & 63;
    si[rr][t] = idxL[(size_t)(row0 + rr) * TK + t];
    sv[rr][t] = valL[(size_t)(row0 + rr) * TK + t];
  }
  __syncthreads();

  float4 a = *(const float4*)(bd + d);
#pragma unroll 8
  for (int t = 0; t < TK; ++t) {
    const int f = si[r][t];
    const float v = sv[r][t];
    ushort4 wv = *(const ushort4*)(Wdb + (size_t)f * DDIM + d);
    a.x = fmaf(v, bf2f(wv.x), a.x);
    a.y = fmaf(v, bf2f(wv.y), a.y);
    a.z = fmaf(v, bf2f(wv.z), a.z);
    a.w = fmaf(v, bf2f(wv.w), a.w);
  }
  *(float4*)(out + (size_t)(row0 + r) * DDIM + d) = a;
}

// ---------------------------------------------------------------------------
extern "C" void kernel_launch(void* const* d_in, const int* in_sizes, int n_in,
                              void* d_out, int out_size, void* d_ws, size_t ws_size,
                              hipStream_t stream) {
  const float* x    = (const float*)d_in[0];
  const float* Wenc = (const float*)d_in[1];
  const float* benc = (const float*)d_in[2];
  const float* Wdec = (const float*)d_in[3];
  const float* bdec = (const float*)d_in[4];
  float* out = (float*)d_out;

  const int D = in_sizes[4];          // 2048
  const int B = in_sizes[0] / D;      // 8192

  // ws layout: idx | val | Wt_f32 | Wt_bf16 | x_h | Wd_b | counts | slots
  char* ws = (char*)d_ws;
  size_t off = 0;
  int*   idxL = (int*)ws;            off += (size_t)B * TK * 4;
  float* valL = (float*)(ws + off);  off += (size_t)B * TK * 4;
  off = (off + 255) & ~(size_t)255;
  float*          wtf = (float*)(ws + off);          off += (size_t)FDIM * DDIM * 4;
  unsigned short* wth = (unsigned short*)(ws + off); off += (size_t)FDIM * DDIM * 2;
  unsigned short* xh  = (unsigned short*)(ws + off); off += (size_t)B * DDIM * 2;
  unsigned short* wdb = (unsigned short*)(ws + off); off += (size_t)FDIM * DDIM * 2;
  off = (off + 255) & ~(size_t)255;
  unsigned char*  cntG = (unsigned char*)(ws + off); off += (size_t)128 * B;
  off = (off + 255) & ~(size_t)255;
  uint2*          slots = (uint2*)(ws + off);        off += (size_t)B * 128 * SLOTS * 8;

  conv_x<<<1024, 256, 0, stream>>>(x, xh, B * D / 4);
  conv_w<<<dim3(FDIM / 32, DDIM / 32), 256, 0, stream>>>(Wenc, wtf, wth);
  conv_wd<<<2048, 256, 0, stream>>>(Wdec, wdb, FDIM * DDIM / 4);

  dim3 g(FDIM / 256, B / 256);
  enc_gemm_bf16<<<g, 512, 0, stream>>>(xh, wth, benc, cntG, slots, B);
  topk_kernel<<<B, 256, 0, stream>>>(cntG, slots, x, wtf, benc,
                                     idxL, valL, B);
  decode_kernel<<<(DDIM / 128) * (B / 4), 128, 0, stream>>>(
      idxL, valL, wdb, bdec, out, B / 4);
}

// Round 16
// 1178.159 us; speedup vs baseline: 4.9825x; 1.0006x over previous
//
#include <hip/hip_runtime.h>
#include <hip/hip_bf16.h>
#include <stdint.h>

#define TK 64
#define FDIM 16384
#define DDIM 2048
#define NCAP 128
#define CCAP 384
#define SLOTS 12
#define TCAND 2.25f

typedef __attribute__((ext_vector_type(8))) short bf16x8;
typedef __attribute__((ext_vector_type(4))) float f32x4;

#define GLL(g, p)                                                        \
  __builtin_amdgcn_global_load_lds(                                      \
      (const __attribute__((address_space(1))) uint32_t*)(g),            \
      (__attribute__((address_space(3))) uint32_t*)(p), 16, 0, 0)

__device__ __forceinline__ unsigned short f2bf(float a) {
  union { float f; uint32_t u; } p; p.f = a;
  uint32_t u = p.u;
  return (unsigned short)((u + 0x7FFFu + ((u >> 16) & 1u)) >> 16);
}
__device__ __forceinline__ float bf2f(unsigned short h) {
  union { uint32_t u; float f; } p; p.u = ((uint32_t)h) << 16; return p.f;
}

// ---------------------------------------------------------------------------
__global__ __launch_bounds__(256) void conv_x(
    const float* __restrict__ x, unsigned short* __restrict__ xh, int n4)
{
  int i = blockIdx.x * 256 + threadIdx.x;
  const int stride = gridDim.x * 256;
  for (; i < n4; i += stride) {
    float4 v = ((const float4*)x)[i];
    ushort4 h;
    h.x = f2bf(v.x); h.y = f2bf(v.y); h.z = f2bf(v.z); h.w = f2bf(v.w);
    ((ushort4*)xh)[i] = h;
  }
}

// ---------------------------------------------------------------------------
__global__ __launch_bounds__(256) void conv_w(
    const float* __restrict__ W, float* __restrict__ wtf,
    unsigned short* __restrict__ wh)
{
  __shared__ float t[32][33];
  const int f0 = blockIdx.x * 32, d0 = blockIdx.y * 32;
  const int tr = threadIdx.x >> 3;
  const int tc = (threadIdx.x & 7) * 4;
  float4 v = *(const float4*)(W + (size_t)(d0 + tr) * FDIM + f0 + tc);
  t[tr][tc + 0] = v.x; t[tr][tc + 1] = v.y;
  t[tr][tc + 2] = v.z; t[tr][tc + 3] = v.w;
  __syncthreads();
  float a0 = t[tc + 0][tr], a1 = t[tc + 1][tr];
  float a2 = t[tc + 2][tr], a3 = t[tc + 3][tr];
  *(float4*)(wtf + (size_t)(f0 + tr) * DDIM + d0 + tc) =
      make_float4(a0, a1, a2, a3);
  ushort4 h;
  h.x = f2bf(a0); h.y = f2bf(a1); h.z = f2bf(a2); h.w = f2bf(a3);
  *(ushort4*)(wh + (size_t)(f0 + tr) * DDIM + d0 + tc) = h;
}

// ---------------------------------------------------------------------------
__global__ __launch_bounds__(256) void conv_wd(
    const float* __restrict__ W, unsigned short* __restrict__ Wb, int n4)
{
  int i = blockIdx.x * 256 + threadIdx.x;
  const int stride = gridDim.x * 256;
  for (; i < n4; i += stride) {
    float4 v = ((const float4*)W)[i];
    ushort4 h;
    h.x = f2bf(v.x); h.y = f2bf(v.y); h.z = f2bf(v.z); h.w = f2bf(v.w);
    ((ushort4*)Wb)[i] = h;
  }
}

// ---------------------------------------------------------------------------
// Kernel 1: encode GEMM — R12 schedule (4-buf ring, counted vmcnt(8), one
// barrier/K-step) with ONE change: B-fragments (bg) are read BEFORE the
// A-fragments (af). lgkmcnt completion is in-order, so with af-first the
// first MFMA waited on 9/12 reads (measured: LDS and MFMA phases fully
// serialized, 2712 cyc/K-step ~ 1129+1242+sync). bg-first lets MFMA row m
// start after read 5+m — reads and MFMAs pipeline within the window.
// ---------------------------------------------------------------------------
#define STAGE(T) do {                                                        \
    const int rb_ = (T) & 3;                                                 \
    const size_t ko_ = (size_t)(T) * 64;                                     \
    const size_t rA0 = (size_t)(row0 + sr4) * 4096 + ko_ + sgo;              \
    GLL(gx + rA0, smem + rb_ * 32768 + wq);                                  \
    const size_t rB0 = (size_t)(col0 + sr4) * 4096 + ko_ + sgo;              \
    GLL(gw + rB0, smem + rb_ * 32768 + 16384 + wq);                          \
    const size_t rA1 = (size_t)(row0 + 128 + sr4) * 4096 + ko_ + sgo;        \
    GLL(gx + rA1, smem + rb_ * 32768 + 8192 + wq);                           \
    const size_t rB1 = (size_t)(col0 + 128 + sr4) * 4096 + ko_ + sgo;        \
    GLL(gw + rB1, smem + rb_ * 32768 + 16384 + 8192 + wq);                   \
  } while (0)

#define KSTEP(S, VMC, DOSTAGE) do {                                          \
    asm volatile("s_waitcnt vmcnt(" #VMC ")" ::: "memory");                  \
    __builtin_amdgcn_s_barrier();                                            \
    const char* tb_ = smem + ((S) & 3) * 32768;                              \
    bf16x8 af[8], bg[4];                                                     \
    _Pragma("unroll") for (int n = 0; n < 4; ++n)                            \
      bg[n] = *(const bf16x8*)(tb_ + 16384 + bwn + n * 1024 + lb);           \
    _Pragma("unroll") for (int m = 0; m < 8; ++m)                            \
      af[m] = *(const bf16x8*)(tb_ + awm + m * 1024 + lb);                   \
    if (DOSTAGE) STAGE((S) + 3);                                             \
    __builtin_amdgcn_s_setprio(1);                                           \
    _Pragma("unroll") for (int m = 0; m < 8; ++m)                            \
      _Pragma("unroll") for (int n = 0; n < 4; ++n)                          \
        acc[m][n] = __builtin_amdgcn_mfma_f32_16x16x32_bf16(                 \
            af[m], bg[n], acc[m][n], 0, 0, 0);                               \
    __builtin_amdgcn_s_setprio(0);                                           \
  } while (0)

__global__ __launch_bounds__(512, 2) void enc_gemm_bf16(
    const unsigned short* __restrict__ xh,  // [B][DDIM] bf16
    const unsigned short* __restrict__ wh,  // [FDIM][DDIM] bf16 (W^T)
    const float* __restrict__ bias,         // [FDIM]
    unsigned char* __restrict__ counts,     // [128 cb][B]
    uint2* __restrict__ slots,              // [B][128 cb][SLOTS]
    int B)
{
  __shared__ __align__(16) char smem[131072];  // 4 ring bufs x (A16K + B16K)
  const int tid = threadIdx.x;
  const int l = tid & 63;
  const int w = tid >> 6;                  // 8 waves
  const int wm = w >> 2, wn = w & 3;       // 2 x 4

  // XCD swizzle + panel-major decode (panel = 2 col-tiles = 512 cols = 2MB)
  const int nbx = gridDim.x;               // 64 col-tiles
  const int nby = gridDim.y;               // 32 row-tiles
  const int lin = blockIdx.y * nbx + blockIdx.x;
  const int nwg = nbx * nby;               // 2048, %8 == 0
  const int cpx = nwg >> 3;
  const int swz = (lin & 7) * cpx + (lin >> 3);
  const int pstripe = 2 * nby;
  const int p  = swz / pstripe;
  const int rm = swz % pstripe;
  const int row0 = (rm >> 1) * 256;
  const int col0 = (p * 2 + (rm & 1)) * 256;

  f32x4 acc[8][4] = {};

  const int sr4 = tid >> 2;                          // 0..127
  const int sg  = (tid & 3) ^ ((sr4 >> 1) & 3);
  const size_t sgo = (size_t)sg * 16;
  const int wq = w * 1024;                           // wave-uniform LDS base
  const char* gx = (const char*)xh;
  const char* gw = (const char*)wh;

  const int lb  = (l & 15) * 64 + (((l >> 4) ^ ((l >> 1) & 3)) << 4);
  const int awm = wm * 8192;
  const int bwn = wn * 4096;

  STAGE(0); STAGE(1); STAGE(2);

  for (int s = 0; s < 61; ++s) KSTEP(s, 8, 1);
  KSTEP(61, 8, 0);
  KSTEP(62, 4, 0);
  KSTEP(63, 0, 0);

  // ---- epilogue: bias + relu + slot emit (256 rows x 2 col-blocks) ----
  __syncthreads();
  uint32_t* rcnt = (uint32_t*)smem;        // 512 counters: [lr][half]
  rcnt[tid] = 0;
  __syncthreads();

#pragma unroll
  for (int n = 0; n < 4; ++n) {
    const int col = col0 + wn * 64 + n * 16 + (l & 15);
    const float bb = bias[col];
    const int half = wn >> 1;
#pragma unroll
    for (int m = 0; m < 8; ++m) {
#pragma unroll
      for (int q = 0; q < 4; ++q) {
        const float zf = acc[m][n][q] + bb;   // > TCAND implies > 0 (relu)
        if (zf > TCAND) {
          const int lr = wm * 128 + m * 16 + (l >> 4) * 4 + q;
          const uint32_t ps = atomicAdd(&rcnt[lr * 2 + half], 1u);
          if (ps < SLOTS) {
            uint2 rec; rec.x = (uint32_t)col; rec.y = __float_as_uint(zf);
            slots[((size_t)(row0 + lr) * 128 + (col0 >> 7) + half) * SLOTS + ps]
                = rec;
          }
        }
      }
    }
  }
  __syncthreads();
  {
    const int lr = tid >> 1, half = tid & 1;
    uint32_t c = rcnt[tid];
    counts[(size_t)((col0 >> 7) + half) * B + row0 + lr] =
        (unsigned char)(c > 255u ? 255u : c);
  }
}

// ---------------------------------------------------------------------------
// Kernel 2: per-row exact top-64 from slot lists (verified R10-R15).
// ---------------------------------------------------------------------------
__global__ __launch_bounds__(256) void topk_kernel(
    const unsigned char* __restrict__ countsG,  // [128][B]
    const uint2* __restrict__ slotsG,           // [B][128][SLOTS]
    const float* __restrict__ x,                // [B][DDIM]
    const float* __restrict__ wtf,              // [FDIM][DDIM] f32 (W^T)
    const float* __restrict__ benc,             // [FDIM]
    int*   __restrict__ outIdx,                 // [B][TK]
    float* __restrict__ outVal,
    int B)
{
  const int row = blockIdx.x;
  const int tid = threadIdx.x;
  const float* xr = x + (size_t)row * DDIM;
  const uint2* slotsRow = slotsG + (size_t)row * 128 * SLOTS;

  __shared__ int    cnts[128];
  __shared__ int    sSum, sMax;
  __shared__ int    cIdx[CCAP];
  __shared__ float  cVal[CCAP];
  __shared__ short  sRank[CCAP];
  __shared__ unsigned char selF[CCAP];
  __shared__ int    cnt;
  __shared__ float  sV64;
  __shared__ int    wList[NCAP];
  __shared__ int    nW, winSel;
  __shared__ double dVals[NCAP];
  __shared__ int    keepFlag[NCAP];
  __shared__ double dred[256];

  if (tid == 0) { sSum = 0; sMax = 0; }
  __syncthreads();
  if (tid < 128) {
    int c = countsG[(size_t)tid * B + row];
    cnts[tid] = c;
    atomicAdd(&sSum, c);
    atomicMax(&sMax, c);
  }
  __syncthreads();
  const int total = sSum;
  bool useSlots = (total >= TK) && (total <= CCAP) && (sMax <= SLOTS);
  float Tlow = TCAND;
  int nc = 0;

  for (int pass = 0; pass < 2; ++pass) {
    if (tid == 0) cnt = 0;
    __syncthreads();
    if (useSlots) {
      for (int s = tid; s < 128 * SLOTS; s += 256) {
        const int cb = s / SLOTS, sl = s - cb * SLOTS;
        if (sl < cnts[cb]) {
          uint2 rec = slotsRow[s];
          int p = atomicAdd(&cnt, 1);
          cIdx[p] = (int)rec.x;
          cVal[p] = __uint_as_float(rec.y);
        }
      }
      __syncthreads();
      nc = cnt;
      __syncthreads();
    } else {
      float Tloc = Tlow;
      for (int attempt = 0; attempt < 16; ++attempt) {
        if (tid == 0) cnt = 0;
        __syncthreads();
        for (int f = tid; f < FDIM; f += 256) {
          const float* wr = wtf + (size_t)f * DDIM;
          float s = 0.f;
          for (int k = 0; k < DDIM; ++k) s = fmaf(xr[k], wr[k], s);
          const float zv = fmaxf(s + benc[f], 0.f);
          if (zv > Tloc) {
            int p = atomicAdd(&cnt, 1);
            if (p < CCAP) { cIdx[p] = f; cVal[p] = zv; }
          }
        }
        __syncthreads();
        nc = cnt;
        __syncthreads();
        if (nc >= TK && nc <= CCAP) break;
        Tloc += (nc > CCAP) ? 0.2f : -0.2f;
      }
      if (nc > CCAP) nc = CCAP;
    }

    for (int c = tid; c < nc; c += 256) {
      const float vi = cVal[c];
      const int   ii = cIdx[c];
      int rk = 0;
      for (int j = 0; j < nc; ++j) {
        const float vj = cVal[j];
        rk += (vj > vi) || (vj == vi && cIdx[j] < ii);
      }
      sRank[c] = (short)rk;
      selF[c] = (rk < TK) ? 1 : 0;
      if (rk == TK - 1) sV64 = vi;
    }
    __syncthreads();

    if (useSlots && sV64 - 0.02f <= TCAND) {
      useSlots = false;
      Tlow = sV64 - 0.04f;
      __syncthreads();
      continue;
    }
    break;
  }

  const float v64 = sV64;
  const float M = 0.02f;

  if (tid == 0) { nW = 0; winSel = 0; }
  __syncthreads();
  for (int c = tid; c < nc; c += 256) {
    if (fabsf(cVal[c] - v64) <= M) {
      int p = atomicAdd(&nW, 1);
      if (p < NCAP) wList[p] = c;
      if (sRank[c] < TK) atomicAdd(&winSel, 1);
    }
  }
  __syncthreads();
  const int nw = (nW < NCAP) ? nW : NCAP;

  if (nw > winSel) {
    for (int c = 0; c < nw; ++c) {
      const int f = cIdx[wList[c]];
      const float* wr = wtf + (size_t)f * DDIM;
      double part = 0.0;
      for (int k = tid; k < DDIM; k += 256)
        part += (double)xr[k] * (double)wr[k];
      dred[tid] = part;
      __syncthreads();
      for (int s = 128; s > 0; s >>= 1) {
        if (tid < s) dred[tid] += dred[tid + s];
        __syncthreads();
      }
      if (tid == 0) dVals[c] = dred[0] + (double)benc[f];
      __syncthreads();
    }
    if (tid == 0) {
      for (int c = 0; c < nw; ++c) keepFlag[c] = 0;
      int take = winSel < nw ? winSel : nw;
      for (int t = 0; t < take; ++t) {
        int best = -1;
        for (int c = 0; c < nw; ++c) {
          if (keepFlag[c]) continue;
          if (best < 0 || dVals[c] > dVals[best] ||
              (dVals[c] == dVals[best] && cIdx[wList[c]] < cIdx[wList[best]]))
            best = c;
        }
        keepFlag[best] = 1;
      }
      for (int c = 0; c < nw; ++c) selF[wList[c]] = (unsigned char)keepFlag[c];
    }
    __syncthreads();
  }

  for (int c = tid; c < nc; c += 256) {
    if (selF[c]) {
      const int myIdx = cIdx[c];
      int pos = 0;
      for (int j = 0; j < nc; ++j)
        pos += (selF[j] && cIdx[j] < myIdx);
      outIdx[(size_t)row * TK + pos] = myIdx;
      outVal[(size_t)row * TK + pos] = cVal[c];
    }
  }
}

// ---------------------------------------------------------------------------
// Kernel 3: decode, slice-major L2 blocking + 4-rows/block ushort4 gathers
// (verified R15).
// ---------------------------------------------------------------------------
__global__ __launch_bounds__(128) void decode_kernel(
    const int*   __restrict__ idxL,
    const float* __restrict__ valL,
    const unsigned short* __restrict__ Wdb,  // [FDIM][DDIM] bf16
    const float* __restrict__ bd,
    float* __restrict__ out,
    int nrowg)                               // B/4 row-groups
{
  const unsigned bid = blockIdx.x;
  const int slice = bid / (unsigned)nrowg;   // slice-major
  const int rg    = bid % (unsigned)nrowg;
  const int row0  = rg * 4;
  const int tid = threadIdx.x;
  const int r  = tid >> 5;                   // row within group (0..3)
  const int d  = slice * 128 + (tid & 31) * 4;

  __shared__ int   si[4][TK];
  __shared__ float sv[4][TK];
  for (int i = tid; i < 4 * TK; i += 128) {
    const int rr = i >> 6, t = i & 63;
    si[rr][t] = idxL[(size_t)(row0 + rr) * TK + t];
    sv[rr][t] = valL[(size_t)(row0 + rr) * TK + t];
  }
  __syncthreads();

  float4 a = *(const float4*)(bd + d);
#pragma unroll 8
  for (int t = 0; t < TK; ++t) {
    const int f = si[r][t];
    const float v = sv[r][t];
    ushort4 wv = *(const ushort4*)(Wdb + (size_t)f * DDIM + d);
    a.x = fmaf(v, bf2f(wv.x), a.x);
    a.y = fmaf(v, bf2f(wv.y), a.y);
    a.z = fmaf(v, bf2f(wv.z), a.z);
    a.w = fmaf(v, bf2f(wv.w), a.w);
  }
  *(float4*)(out + (size_t)(row0 + r) * DDIM + d) = a;
}

// ---------------------------------------------------------------------------
extern "C" void kernel_launch(void* const* d_in, const int* in_sizes, int n_in,
                              void* d_out, int out_size, void* d_ws, size_t ws_size,
                              hipStream_t stream) {
  const float* x    = (const float*)d_in[0];
  const float* Wenc = (const float*)d_in[1];
  const float* benc = (const float*)d_in[2];
  const float* Wdec = (const float*)d_in[3];
  const float* bdec = (const float*)d_in[4];
  float* out = (float*)d_out;

  const int D = in_sizes[4];          // 2048
  const int B = in_sizes[0] / D;      // 8192

  // ws layout: idx | val | Wt_f32 | Wt_bf16 | x_h | Wd_b | counts | slots
  char* ws = (char*)d_ws;
  size_t off = 0;
  int*   idxL = (int*)ws;            off += (size_t)B * TK * 4;
  float* valL = (float*)(ws + off);  off += (size_t)B * TK * 4;
  off = (off + 255) & ~(size_t)255;
  float*          wtf = (float*)(ws + off);          off += (size_t)FDIM * DDIM * 4;
  unsigned short* wth = (unsigned short*)(ws + off); off += (size_t)FDIM * DDIM * 2;
  unsigned short* xh  = (unsigned short*)(ws + off); off += (size_t)B * DDIM * 2;
  unsigned short* wdb = (unsigned short*)(ws + off); off += (size_t)FDIM * DDIM * 2;
  off = (off + 255) & ~(size_t)255;
  unsigned char*  cntG = (unsigned char*)(ws + off); off += (size_t)128 * B;
  off = (off + 255) & ~(size_t)255;
  uint2*          slots = (uint2*)(ws + off);        off += (size_t)B * 128 * SLOTS * 8;

  conv_x<<<1024, 256, 0, stream>>>(x, xh, B * D / 4);
  conv_w<<<dim3(FDIM / 32, DDIM / 32), 256, 0, stream>>>(Wenc, wtf, wth);
  conv_wd<<<2048, 256, 0, stream>>>(Wdec, wdb, FDIM * DDIM / 4);

  dim3 g(FDIM / 256, B / 256);
  enc_gemm_bf16<<<g, 512, 0, stream>>>(xh, wth, benc, cntG, slots, B);
  topk_kernel<<<B, 256, 0, stream>>>(cntG, slots, x, wtf, benc,
                                     idxL, valL, B);
  decode_kernel<<<(DDIM / 128) * (B / 4), 128, 0, stream>>>(
      idxL, valL, wdb, bdec, out, B / 4);
}